// Round 7
// baseline (405.578 us; speedup 1.0000x reference)
//
#include <hip/hip_runtime.h>
#include <stdint.h>

typedef unsigned int u32;
typedef unsigned short u16;

#define DI __device__ __forceinline__

DI float bf2f(u16 h){ return __uint_as_float(((u32)h)<<16); }
// round-half-up bf16: 2 VALU ops (vs 4 for RNE); differs from RNE only on exact ties
DI u16 f2bf(float f){ return (u16)((__float_as_uint(f) + 0x8000u) >> 16); }
DI u32 pack2(float a, float b){
  u32 au = __float_as_uint(a) + 0x8000u;
  u32 bu = __float_as_uint(b) + 0x8000u;
  return (au >> 16) | (bu & 0xFFFF0000u);
}
DI int is_bf16(const void* p){ u32 u = *(const u32*)p; return ((u>>16) == (u & 0xFFFFu)) ? 1 : 0; }

typedef __attribute__((ext_vector_type(8))) short bf16x8;
typedef __attribute__((ext_vector_type(4))) float f32x4;

// ---------------- input table (element counts / offsets in fp32 staging buf) ----------------
#define NIN 29
__device__ const int g_in_off[NIN] = {
  0,27648,158720,289792,291520,291584,439040,439296,586752,587008,734464,
  734720,738816,738880,742976,743040,779904,779968,816832,816896,883456,
  883712,949248,949504,1015040,1015296,1080832,1081088,1081856};
#define CVT_TOTAL 1081859

// cvt-buffer float offsets
#define O_INP      0
#define O_COORD    27648
#define O_CELL     158720
#define O_ENCW     289792
#define O_ENCB     291520
#define O_UP1W     291584
#define O_UP1B     439040
#define O_UP2W     439296
#define O_UP2B     586752
#define O_UP3W     587008
#define O_UP3B     734464
#define O_SK1W     734720
#define O_SK1B     738816
#define O_SK2W     738880
#define O_SK2B     742976
#define O_DN4W     743040
#define O_DN4B     779904
#define O_DN5W     779968
#define O_DN5B     816832
#define O_MLPW0    816896
#define O_MLPB0    883456
#define O_MLPW1    883712
#define O_MLPB1    949248
#define O_MLPW2    949504
#define O_MLPB2    1015040
#define O_MLPW3    1015296
#define O_MLPB3    1080832
#define O_MLPW4    1081088
#define O_MLPB4    1081856

// ---------------- workspace layout (float offsets) ----------------
#define W_CVT    16
#define W_FRAG   1082000     // u16 fragment region (conv + mlp), 798720 u16
// fragment sub-offsets (u16 elements within W_FRAG)
#define FG_UP1 0
#define FG_UP2 147456
#define FG_UP3 294912
#define FG_D4  442368
#define FG_D5  483328
#define CONV_FRAG_TOTAL 524288
#define FG_MLP 524288
// MLP fragment layer offsets (u16, relative to FG_MLP)
#define FO_L0 0
#define FO_L1 73728
#define FO_L2 139264
#define FO_L3 204800
#define FO_L4 270336
#define FRAG_TOTAL 274432
#define REPACK_TOTAL (CONV_FRAG_TOTAL + FRAG_TOTAL)   // 798720 = 3120*256
// feature maps: bf16 NHWC (float offsets; cast to u16*)
#define W_FEAT   1481360    // 48x48x64 x4  -> ends 1776272
#define W_FEAT1  1776272    // 96          -> ends 2955920
#define W_FEAT2  2955920    // 192         -> ends 7674512
#define W_FEAT3  7674512    // 384         -> ends 26548880
#define W_FEAT4  26548880   // 192         -> ends 31267472
#define W_FEAT5  31267472   // 96          -> ends 32447120
// end: 32447120 floats = 129.8 MB

#define AST 296   // Abuf row stride in bf16 (592 B: 16B-aligned, bank step 20 -> <=2-way)

struct Ptrs { const void* p[NIN]; };

__global__ __launch_bounds__(256) void k_convert(Ptrs ptrs, float* __restrict__ dst){
  int idx = blockIdx.x*256 + threadIdx.x;
  if (idx >= CVT_TOTAL) return;
  int bf = is_bf16(ptrs.p[2]);   // cell is constant 2/384: packed-bf16 halves match
  int i = 0;
  #pragma unroll
  for (int s = 1; s < NIN; ++s) if (idx >= g_in_off[s]) i = s;
  int local = idx - g_in_off[i];
  float v;
  if (bf) v = bf2f(((const u16*)ptrs.p[i])[local]);
  else    v = ((const float*)ptrs.p[i])[local];
  dst[idx] = v;
}

// ---------------- merged weight repack -> MFMA B-fragment order (bf16) ----------------
// conv up layers: K=576 (k=(dy*3+dx)*64+ci), N=256, perm co=(wv*16+(col>>2)*4+nt)*4+(col&3)
// conv down layers (fused skip): K=640, N=64, co=nt*16+col
// mlp L0-L3: 16-wide n-tiles, k=kc*32+quad*8+j, n=nt*16+col
__global__ __launch_bounds__(256) void k_repack_all(const float* __restrict__ cvt, u16* __restrict__ dst){
  int idx = blockIdx.x*256 + threadIdx.x;   // covers REPACK_TOTAL exactly
  float v;
  if (idx < 442368){
    int seg = idx / 147456, base = idx % 147456;
    const int wo[3] = {O_UP1W, O_UP2W, O_UP3W};
    int t = base & 511, c = base >> 9;      // c in [0,288)
    int j = t & 7, lane = t >> 3;
    int col = lane & 15, quad = lane >> 4;
    int kc = c >> 4, rem = c & 15;
    int wv = rem >> 2, nt = rem & 3;
    int k = kc*32 + quad*8 + j;             // < 576
    int kid = k >> 6, ci = k & 63;
    int co = (wv*16 + (col>>2)*4 + nt)*4 + (col&3);
    v = cvt[wo[seg] + co*576 + ci*9 + kid];
  } else if (idx < CONV_FRAG_TOTAL){
    int x = idx - 442368;
    int seg = x / 40960, base = x % 40960;
    int t = base & 511, c = base >> 9;      // c in [0,80)
    int j = t & 7, lane = t >> 3;
    int col = lane & 15, quad = lane >> 4;
    int kc = c >> 2, nt = c & 3;
    int k = kc*32 + quad*8 + j;
    int co = nt*16 + col;
    if (k < 576){
      int kid = k >> 6, ci = k & 63;
      v = cvt[(seg ? O_DN5W : O_DN4W) + co*576 + ci*9 + kid];
    } else {
      int ci = k - 576;
      v = cvt[(seg ? O_SK2W : O_SK1W) + co*64 + ci];
    }
  } else {
    int midx = idx - FG_MLP;
    int l, base;
    if (midx < FO_L1)      { l = 0; base = midx; }
    else if (midx < FO_L2) { l = 1; base = midx - FO_L1; }
    else if (midx < FO_L3) { l = 2; base = midx - FO_L2; }
    else if (midx < FO_L4) { l = 3; base = midx - FO_L3; }
    else                   { l = 4; base = midx - FO_L4; }
    int t = base & 511, c = base >> 9;
    int L = t >> 3, j = t & 7;
    int ntiles = (l == 4) ? 1 : 16;
    int kc = c / ntiles, nt = c % ntiles;
    int k = kc*32 + (L>>4)*8 + j;
    int n = nt*16 + (L&15);
    const int srcw[5] = {O_MLPW0, O_MLPW1, O_MLPW2, O_MLPW3, O_MLPW4};
    int Kvalid = (l == 0) ? 260 : 256;
    int N = (l == 4) ? 3 : 256;
    v = 0.f;
    if (k < Kvalid && n < N) v = cvt[srcw[l] + k*N + n];
  }
  dst[idx] = f2bf(v);
}

// ---------------- enc conv: 3->64, 3x3 pad1, NCHW fp32 in, NHWC bf16 out ----------------
__global__ __launch_bounds__(256) void k_enc(const float* __restrict__ cvt, u16* __restrict__ feat){
  int gid = blockIdx.x*256 + threadIdx.x;
  int co = gid & 63, pix = gid >> 6;
  int x = pix % 48; int t = pix / 48; int y = t % 48; int b = t / 48;
  const float* w = cvt + O_ENCW + co*27;
  float acc = cvt[O_ENCB + co];
  const float* ip = cvt + O_INP + b*3*2304;
  #pragma unroll
  for (int ci = 0; ci < 3; ++ci)
    for (int dy = 0; dy < 3; ++dy){
      int iy = y + dy - 1;
      for (int dx = 0; dx < 3; ++dx){
        int ix = x + dx - 1;
        float v = (iy>=0 && iy<48 && ix>=0 && ix<48) ? ip[ci*2304 + iy*48 + ix] : 0.f;
        acc = fmaf(w[ci*9 + dy*3 + dx], v, acc);
      }
    }
  feat[pix*64 + co] = f2bf(acc);
}

// ---------------- MFMA upconv 64->256 3x3 pad1 + fused pixel-shuffle, bf16 NHWC ----------------
template<int H>
__global__ __launch_bounds__(256,2) void k_upconv_mfma(const u16* __restrict__ in,
    const u16* __restrict__ wf, const float* __restrict__ bias, u16* __restrict__ out){
  __shared__ __align__(16) u16 patch[100*72];   // 10x10 px, 64ch + pad8
  const int TW = H/8;
  int b = blockIdx.y;
  int y0 = (blockIdx.x / TW)*8, x0 = (blockIdx.x % TW)*8;
  int tid = threadIdx.x;
  if (tid < 200){
    int p = tid >> 1, half = tid & 1;
    int pr = p/10, pc = p - pr*10;
    int gy = y0+pr-1, gx = x0+pc-1;
    uint4* dst = (uint4*)((char*)(patch + p*72) + half*64);
    if (gy>=0 && gy<H && gx>=0 && gx<H){
      const uint4* src = (const uint4*)((const char*)(in + ((b*H+gy)*H+gx)*64) + half*64);
      dst[0]=src[0]; dst[1]=src[1]; dst[2]=src[2]; dst[3]=src[3];
    } else {
      uint4 z = {0,0,0,0};
      dst[0]=z; dst[1]=z; dst[2]=z; dst[3]=z;
    }
  }
  __syncthreads();
  int lane = tid & 63, wv = __builtin_amdgcn_readfirstlane(tid>>6);
  int col = lane & 15, quad = lane >> 4;
  int rs = col & 3;                       // subpixel from low col bits
  int c2b = wv*16 + (col>>2)*4;           // 4 consecutive output channels per lane
  f32x4 acc[4][4];
  #pragma unroll
  for (int nt=0;nt<4;++nt){
    float bv = bias[(c2b + nt)*4 + rs];
    #pragma unroll
    for (int mt=0;mt<4;++mt) acc[mt][nt] = (f32x4){bv,bv,bv,bv};
  }
  int pyc[4], pxc[4];
  #pragma unroll
  for (int mt=0;mt<4;++mt){ int p = mt*16+col; pyc[mt]=p>>3; pxc[mt]=p&7; }
  #pragma unroll
  for (int kc=0; kc<18; ++kc){
    int dydx = kc>>1, half = kc&1;
    int dy = dydx/3, dx = dydx%3;
    bf16x8 a[4], bb[4];
    #pragma unroll
    for (int mt=0;mt<4;++mt)
      a[mt] = *(const bf16x8*)(patch + ((pyc[mt]+dy)*10 + pxc[mt]+dx)*72 + half*32 + quad*8);
    #pragma unroll
    for (int nt=0;nt<4;++nt)
      bb[nt] = *(const bf16x8*)(wf + ((kc*16 + wv*4 + nt)*64 + lane)*8);
    #pragma unroll
    for (int mt=0;mt<4;++mt)
      #pragma unroll
      for (int nt=0;nt<4;++nt)
        acc[mt][nt] = __builtin_amdgcn_mfma_f32_16x16x32_bf16(a[mt], bb[nt], acc[mt][nt], 0,0,0);
  }
  // store: per (mt,r) the 4 nt-values are channels c2b..c2b+3 at subpixel rs -> one 8B store
  const int W2 = 2*H;
  #pragma unroll
  for (int mt=0;mt<4;++mt)
    #pragma unroll
    for (int r=0;r<4;++r){
      int p = mt*16 + quad*4 + r;
      int oy = 2*(y0 + (p>>3)) + (rs>>1), ox = 2*(x0 + (p&7)) + (rs&1);
      uint2 v2;
      v2.x = pack2(acc[mt][0][r], acc[mt][1][r]);
      v2.y = pack2(acc[mt][2][r], acc[mt][3][r]);
      *(uint2*)(out + ((b*W2 + oy)*W2 + ox)*64 + c2b) = v2;
    }
}

// ---------------- MFMA stride-2 downconv 64->64 + fused 1x1 skip, bf16 NHWC ----------------
template<int HO>
__global__ __launch_bounds__(256,2) void k_down_mfma(const u16* __restrict__ in3,
    const u16* __restrict__ in2, const u16* __restrict__ wf,
    const float* __restrict__ biasd, const float* __restrict__ biass, u16* __restrict__ out){
  __shared__ __align__(16) u16 patch3[289*72];  // 17x17 px
  __shared__ __align__(16) u16 patch2[64*72];   // 8x8 px (skip input)
  const int HI = 2*HO, TW = HO/8;
  int b = blockIdx.y;
  int y0 = (blockIdx.x / TW)*8, x0 = (blockIdx.x % TW)*8;
  int tid = threadIdx.x;
  for (int u = tid; u < 578; u += 256){
    int p = u >> 1, half = u & 1;
    int pr = p/17, pc = p - pr*17;
    int gy = 2*y0 - 1 + pr, gx = 2*x0 - 1 + pc;
    uint4* dst = (uint4*)((char*)(patch3 + p*72) + half*64);
    if (gy>=0 && gy<HI && gx>=0 && gx<HI){
      const uint4* src = (const uint4*)((const char*)(in3 + ((b*HI+gy)*HI+gx)*64) + half*64);
      dst[0]=src[0]; dst[1]=src[1]; dst[2]=src[2]; dst[3]=src[3];
    } else { uint4 z={0,0,0,0}; dst[0]=z; dst[1]=z; dst[2]=z; dst[3]=z; }
  }
  if (tid < 128){
    int p = tid >> 1, half = tid & 1;
    int gy = y0 + (p>>3), gx = x0 + (p&7);
    uint4* dst = (uint4*)((char*)(patch2 + p*72) + half*64);
    const uint4* src = (const uint4*)((const char*)(in2 + ((b*HO+gy)*HO+gx)*64) + half*64);
    dst[0]=src[0]; dst[1]=src[1]; dst[2]=src[2]; dst[3]=src[3];
  }
  __syncthreads();
  int lane = tid & 63, wv = __builtin_amdgcn_readfirstlane(tid>>6);
  int col = lane & 15, quad = lane >> 4;
  f32x4 acc[4];
  {
    float bv = biasd[wv*16+col] + biass[wv*16+col];
    #pragma unroll
    for (int mt=0;mt<4;++mt) acc[mt] = (f32x4){bv,bv,bv,bv};
  }
  int pyc[4], pxc[4];
  #pragma unroll
  for (int mt=0;mt<4;++mt){ int p = mt*16+col; pyc[mt]=p>>3; pxc[mt]=p&7; }
  #pragma unroll
  for (int kc=0; kc<20; ++kc){
    bf16x8 a[4];
    if (kc < 18){
      int dydx = kc>>1, half = kc&1;
      int dy = dydx/3, dx = dydx%3;
      #pragma unroll
      for (int mt=0;mt<4;++mt)
        a[mt] = *(const bf16x8*)(patch3 + ((2*pyc[mt]+dy)*17 + 2*pxc[mt]+dx)*72 + half*32 + quad*8);
    } else {
      #pragma unroll
      for (int mt=0;mt<4;++mt)
        a[mt] = *(const bf16x8*)(patch2 + (pyc[mt]*8+pxc[mt])*72 + (kc-18)*32 + quad*8);
    }
    bf16x8 bb = *(const bf16x8*)(wf + ((kc*4 + wv)*64 + lane)*8);
    #pragma unroll
    for (int mt=0;mt<4;++mt)
      acc[mt] = __builtin_amdgcn_mfma_f32_16x16x32_bf16(a[mt], bb, acc[mt], 0,0,0);
  }
  #pragma unroll
  for (int mt=0;mt<4;++mt)
    #pragma unroll
    for (int r=0;r<4;++r){
      int p = mt*16 + quad*4 + r;
      out[((b*HO + y0+(p>>3))*HO + x0+(p&7))*64 + wv*16+col] = f2bf(acc[mt][r]);
    }
}

// ---------------- query stage helpers (fp32 op sequence matched to numpy) ----------------
DI void shifted_coord(float cy, float cx, int e, float& cy_, float& cx_){
  float vx = (e & 2) ? 1.f : -1.f;
  float vy = (e & 1) ? 1.f : -1.f;
  float sy = (float)((double)vx*(1.0/48.0) + 1e-6);
  float sx = (float)((double)vy*(1.0/48.0) + 1e-6);
  const float clo = (float)(-1.0 + 1e-6), chi = (float)(1.0 - 1e-6);
  cy_ = fminf(fmaxf(__fadd_rn(cy, sy), clo), chi);
  cx_ = fminf(fmaxf(__fadd_rn(cx, sx), clo), chi);
}
DI int nidx(float c_, int hL){
  float f = __fadd_rn(__fmul_rn(__fadd_rn(c_, 1.f), (float)hL*0.5f), -0.5f);
  int i = (int)rintf(f);
  return max(0, min(hL-1, i));
}

// ---------------- MFMA MLP layer helpers (16x16x32) ----------------
template<int KC>
DI void layer_compute(const u16* __restrict__ Ab, const u16* __restrict__ wf,
                      const float* __restrict__ bias, int lane, int wv, f32x4 (&acc)[4][4]){
  int col = lane & 15, quad = lane >> 4;
  #pragma unroll
  for (int mt=0;mt<4;++mt)
    #pragma unroll
    for (int nt=0;nt<4;++nt){
      float bv = bias[wv*64 + nt*16 + col];
      acc[mt][nt] = (f32x4){bv,bv,bv,bv};
    }
  for (int kc=0; kc<KC; ++kc){
    bf16x8 a[4], b[4];
    #pragma unroll
    for (int mt=0;mt<4;++mt)
      a[mt] = *(const bf16x8*)(Ab + (mt*16+col)*AST + kc*32 + quad*8);
    #pragma unroll
    for (int nt=0;nt<4;++nt)
      b[nt] = *(const bf16x8*)(wf + ((kc*16 + wv*4 + nt)*64 + lane)*8);
    #pragma unroll
    for (int mt=0;mt<4;++mt)
      #pragma unroll
      for (int nt=0;nt<4;++nt)
        acc[mt][nt] = __builtin_amdgcn_mfma_f32_16x16x32_bf16(a[mt], b[nt], acc[mt][nt], 0, 0, 0);
  }
}

DI void layer_store(u16* __restrict__ Ab, f32x4 (&acc)[4][4], int lane, int wv){
  int col = lane & 15, quad = lane >> 4;
  #pragma unroll
  for (int mt=0;mt<4;++mt)
    #pragma unroll
    for (int nt=0;nt<4;++nt)
      #pragma unroll
      for (int r=0;r<4;++r){
        u32 u = __float_as_uint(fmaxf(acc[mt][nt][r], 0.f)) + 0x8000u;
        Ab[(mt*16 + quad*4 + r)*AST + wv*64 + nt*16 + col] = (u16)(u >> 16);
      }
}

// ---------------- fused gather + MFMA MLP + ensemble + bilinear ----------------
__global__ __launch_bounds__(256) void k_query(const float* __restrict__ cvt,
    const u16* __restrict__ feat, const u16* __restrict__ feat3,
    const u16* __restrict__ feat4, const u16* __restrict__ feat5,
    const u16* __restrict__ wfrag, const void* __restrict__ cellraw, void* __restrict__ outv){
  __shared__ __align__(16) u16 Abuf[64*AST];      // 37888 B, [row m][k]
  __shared__ float predbuf[64*3];
  int tid = threadIdx.x;

  // ---- gather: 64 rows (16 queries x 4 ensembles), 4 parts/row = 4 pyramid levels ----
  {
    int r = tid >> 2, part = tid & 3;
    int gq = blockIdx.x*16 + (r>>2);
    int e = r & 3;
    int b = gq >> 14, q = gq & 16383;
    float cy = cvt[O_COORD + (b*16384+q)*2 + 0];
    float cx = cvt[O_COORD + (b*16384+q)*2 + 1];
    float cy_, cx_; shifted_coord(cy, cx, e, cy_, cx_);
    int hL = (part==0) ? 48 : (part==1) ? 96 : (part==2) ? 192 : 384;
    const u16* fp = (part==0) ? feat : (part==1) ? feat5 : (part==2) ? feat4 : feat3;
    int iy = nidx(cy_, hL), ix = nidx(cx_, hL);
    const uint4* src = (const uint4*)(fp + ((b*hL + iy)*hL + ix)*64);
    uint4* dst = (uint4*)((char*)Abuf + r*(AST*2) + part*128);
    #pragma unroll
    for (int i=0;i<8;++i) dst[i] = src[i];
  }
  // ---- rel features into K=256..259, zeros to 287 (layer-0 K padded to 288) ----
  if (tid < 64){
    int gq = blockIdx.x*16 + (tid>>2);
    int e = tid & 3;
    int b = gq >> 14, q = gq & 16383;
    float cy = cvt[O_COORD + (b*16384+q)*2 + 0];
    float cx = cvt[O_COORD + (b*16384+q)*2 + 1];
    float cy_, cx_; shifted_coord(cy, cx, e, cy_, cx_);
    int iy = nidx(cy_, 48), ix = nidx(cx_, 48);
    float qy = -1.f + (2.f*iy + 1.f)*(1.f/48.f);
    float qx = -1.f + (2.f*ix + 1.f)*(1.f/48.f);
    float r0 = (cy - qy)*48.f;
    float r1 = (cx - qx)*48.f;
    float r2 = cvt[O_CELL + (b*16384+q)*2 + 0]*48.f;
    float r3 = cvt[O_CELL + (b*16384+q)*2 + 1]*48.f;
    u32* dst = (u32*)((char*)Abuf + tid*(AST*2) + 512);
    dst[0] = pack2(r0, r1);
    dst[1] = pack2(r2, r3);
    #pragma unroll
    for (int z=0; z<14; ++z) dst[2+z] = 0u;
  }
  __syncthreads();

  int lane = tid & 63;
  int wv = __builtin_amdgcn_readfirstlane(tid >> 6);

  { f32x4 acc[4][4];
    layer_compute<9>(Abuf, wfrag + FO_L0, cvt + O_MLPB0, lane, wv, acc);
    __syncthreads(); layer_store(Abuf, acc, lane, wv); }
  __syncthreads();
  { f32x4 acc[4][4];
    layer_compute<8>(Abuf, wfrag + FO_L1, cvt + O_MLPB1, lane, wv, acc);
    __syncthreads(); layer_store(Abuf, acc, lane, wv); }
  __syncthreads();
  { f32x4 acc[4][4];
    layer_compute<8>(Abuf, wfrag + FO_L2, cvt + O_MLPB2, lane, wv, acc);
    __syncthreads(); layer_store(Abuf, acc, lane, wv); }
  __syncthreads();
  { f32x4 acc[4][4];
    layer_compute<8>(Abuf, wfrag + FO_L3, cvt + O_MLPB3, lane, wv, acc);
    __syncthreads(); layer_store(Abuf, acc, lane, wv); }
  __syncthreads();

  // ---- layer 4 (256->3): wave wv handles m-tile wv ----
  {
    int col = lane & 15, quad = lane >> 4;
    float bv = (col < 3) ? cvt[O_MLPB4 + col] : 0.f;
    f32x4 a4 = (f32x4){bv,bv,bv,bv};
    for (int kc=0; kc<8; ++kc){
      bf16x8 av = *(const bf16x8*)(Abuf + (wv*16 + col)*AST + kc*32 + quad*8);
      bf16x8 bv8 = *(const bf16x8*)(wfrag + FO_L4 + (kc*64 + lane)*8);
      a4 = __builtin_amdgcn_mfma_f32_16x16x32_bf16(av, bv8, a4, 0, 0, 0);
    }
    if (col < 3){
      #pragma unroll
      for (int r=0;r<4;++r)
        predbuf[(wv*16 + quad*4 + r)*3 + col] = a4[r];
    }
  }
  __syncthreads();

  // ---- ensemble combine + bilinear(inp) + store ----
  if (tid < 16){
    int gq = blockIdx.x*16 + tid;
    int b = gq >> 14, q = gq & 16383;
    float cy = cvt[O_COORD + (b*16384+q)*2 + 0];
    float cx = cvt[O_COORD + (b*16384+q)*2 + 1];
    float a[4];
    #pragma unroll
    for (int e=0;e<4;++e){
      float cy_, cx_; shifted_coord(cy, cx, e, cy_, cx_);
      int iy = nidx(cy_, 48), ix = nidx(cx_, 48);
      float qy = -1.f + (2.f*iy + 1.f)*(1.f/48.f);
      float qx = -1.f + (2.f*ix + 1.f)*(1.f/48.f);
      float ry = (cy - qy)*48.f, rx = (cx - qx)*48.f;
      a[e] = fabsf(ry*rx) + 1e-9f;
    }
    float tot = a[0]+a[1]+a[2]+a[3];
    float fy = fminf(fmaxf((cy+1.f)*24.f - 0.5f, 0.f), 47.f);
    float fx = fminf(fmaxf((cx+1.f)*24.f - 0.5f, 0.f), 47.f);
    float y0f = floorf(fy), x0f = floorf(fx);
    float wy = fy - y0f, wx = fx - x0f;
    int y0 = (int)y0f, x0 = (int)x0f;
    int y1 = min(y0+1, 47), x1 = min(x0+1, 47);
    int bf = is_bf16(cellraw);
    #pragma unroll
    for (int ch=0; ch<3; ++ch){
      const float* ip = cvt + O_INP + (b*3 + ch)*2304;
      float v00 = ip[y0*48+x0], v01 = ip[y0*48+x1], v10 = ip[y1*48+x0], v11 = ip[y1*48+x1];
      float v = v00*(1.f-wy)*(1.f-wx) + v01*(1.f-wy)*wx + v10*wy*(1.f-wx) + v11*wy*wx;
      #pragma unroll
      for (int e=0;e<4;++e)
        v += predbuf[(tid*4+e)*3 + ch] * (a[3-e]/tot);   // local-ensemble diagonal swap
      int oi = (b*16384+q)*3 + ch;
      if (bf) ((u16*)outv)[oi] = f2bf(v);
      else    ((float*)outv)[oi] = v;
    }
  }
}

extern "C" void kernel_launch(void* const* d_in, const int* in_sizes, int n_in,
                              void* d_out, int out_size, void* d_ws, size_t ws_size,
                              hipStream_t stream){
  float* ws = (float*)d_ws;
  float* cvt = ws + W_CVT;
  u16* frag = (u16*)(ws + W_FRAG);
  u16* feat  = (u16*)(ws + W_FEAT);
  u16* feat1 = (u16*)(ws + W_FEAT1);
  u16* feat2 = (u16*)(ws + W_FEAT2);
  u16* feat3 = (u16*)(ws + W_FEAT3);
  u16* feat4 = (u16*)(ws + W_FEAT4);
  u16* feat5 = (u16*)(ws + W_FEAT5);
  Ptrs ptrs;
  for (int i = 0; i < NIN && i < n_in; ++i) ptrs.p[i] = d_in[i];

  k_convert<<<(CVT_TOTAL+255)/256, 256, 0, stream>>>(ptrs, cvt);
  k_repack_all<<<REPACK_TOTAL/256, 256, 0, stream>>>(cvt, frag);
  k_enc<<<2304, 256, 0, stream>>>(cvt, feat);
  k_upconv_mfma<48> <<<dim3(36, 4), 256, 0, stream>>>(feat,  frag+FG_UP1, cvt+O_UP1B, feat1);
  k_upconv_mfma<96> <<<dim3(144,4), 256, 0, stream>>>(feat1, frag+FG_UP2, cvt+O_UP2B, feat2);
  k_upconv_mfma<192><<<dim3(576,4), 256, 0, stream>>>(feat2, frag+FG_UP3, cvt+O_UP3B, feat3);
  k_down_mfma<192><<<dim3(576,4), 256, 0, stream>>>(feat3, feat2, frag+FG_D4, cvt+O_DN4B, cvt+O_SK1B, feat4);
  k_down_mfma<96> <<<dim3(144,4), 256, 0, stream>>>(feat4, feat1, frag+FG_D5, cvt+O_DN5B, cvt+O_SK2B, feat5);
  k_query<<<4096, 256, 0, stream>>>(cvt, feat, feat3, feat4, feat5, frag + FG_MLP, d_in[2], d_out);
}

// Round 8
// 395.131 us; speedup vs baseline: 1.0264x; 1.0264x over previous
//
#include <hip/hip_runtime.h>
#include <stdint.h>

typedef unsigned int u32;
typedef unsigned short u16;

#define DI __device__ __forceinline__

DI float bf2f(u16 h){ return __uint_as_float(((u32)h)<<16); }
// round-half-up bf16: 2 VALU ops (vs 4 for RNE); differs from RNE only on exact ties
DI u16 f2bf(float f){ return (u16)((__float_as_uint(f) + 0x8000u) >> 16); }
DI u32 pack2(float a, float b){
  u32 au = __float_as_uint(a) + 0x8000u;
  u32 bu = __float_as_uint(b) + 0x8000u;
  return (au >> 16) | (bu & 0xFFFF0000u);
}
DI int is_bf16(const void* p){ u32 u = *(const u32*)p; return ((u>>16) == (u & 0xFFFFu)) ? 1 : 0; }

typedef __attribute__((ext_vector_type(8))) short bf16x8;
typedef __attribute__((ext_vector_type(4))) float f32x4;

// ---------------- input table (element counts / offsets in fp32 staging buf) ----------------
#define NIN 29
__device__ const int g_in_off[NIN] = {
  0,27648,158720,289792,291520,291584,439040,439296,586752,587008,734464,
  734720,738816,738880,742976,743040,779904,779968,816832,816896,883456,
  883712,949248,949504,1015040,1015296,1080832,1081088,1081856};
#define CVT_TOTAL 1081859

// cvt-buffer float offsets
#define O_INP      0
#define O_COORD    27648
#define O_CELL     158720
#define O_ENCW     289792
#define O_ENCB     291520
#define O_UP1W     291584
#define O_UP1B     439040
#define O_UP2W     439296
#define O_UP2B     586752
#define O_UP3W     587008
#define O_UP3B     734464
#define O_SK1W     734720
#define O_SK1B     738816
#define O_SK2W     738880
#define O_SK2B     742976
#define O_DN4W     743040
#define O_DN4B     779904
#define O_DN5W     779968
#define O_DN5B     816832
#define O_MLPW0    816896
#define O_MLPB0    883456
#define O_MLPW1    883712
#define O_MLPB1    949248
#define O_MLPW2    949504
#define O_MLPB2    1015040
#define O_MLPW3    1015296
#define O_MLPB3    1080832
#define O_MLPW4    1081088
#define O_MLPB4    1081856

// ---------------- workspace layout (float offsets) ----------------
#define W_CVT    16
#define W_FRAG   1082000     // u16 fragment region (conv + mlp), 798720 u16
// fragment sub-offsets (u16 elements within W_FRAG)
#define FG_UP1 0
#define FG_UP2 147456
#define FG_UP3 294912
#define FG_D4  442368
#define FG_D5  483328
#define CONV_FRAG_TOTAL 524288
#define FG_MLP 524288
// MLP fragment layer offsets (u16, relative to FG_MLP)
#define FO_L0 0
#define FO_L1 73728
#define FO_L2 139264
#define FO_L3 204800
#define FO_L4 270336
#define FRAG_TOTAL 274432
#define REPACK_TOTAL (CONV_FRAG_TOTAL + FRAG_TOTAL)   // 798720 = 3120*256
// feature maps: bf16 NHWC (float offsets; cast to u16*)
#define W_FEAT   1481360    // 48x48x64 x4  -> ends 1776272
#define W_FEAT1  1776272    // 96          -> ends 2955920
#define W_FEAT2  2955920    // 192         -> ends 7674512
#define W_FEAT3  7674512    // 384         -> ends 26548880
#define W_FEAT4  26548880   // 192         -> ends 31267472
#define W_FEAT5  31267472   // 96          -> ends 32447120
// end: 32447120 floats = 129.8 MB

#define AST 296   // Abuf row stride in bf16 (592 B: 16B-aligned, bank step 20 -> <=2-way)

struct Ptrs { const void* p[NIN]; };

__global__ __launch_bounds__(256) void k_convert(Ptrs ptrs, float* __restrict__ dst){
  int idx = blockIdx.x*256 + threadIdx.x;
  if (idx >= CVT_TOTAL) return;
  int bf = is_bf16(ptrs.p[2]);   // cell is constant 2/384: packed-bf16 halves match
  int i = 0;
  #pragma unroll
  for (int s = 1; s < NIN; ++s) if (idx >= g_in_off[s]) i = s;
  int local = idx - g_in_off[i];
  float v;
  if (bf) v = bf2f(((const u16*)ptrs.p[i])[local]);
  else    v = ((const float*)ptrs.p[i])[local];
  dst[idx] = v;
}

// ---------------- merged weight repack -> MFMA fragment order (bf16) ----------------
// conv up layers: K=576 (k=(dy*3+dx)*64+ci), N=256, perm co=(wv*16+(col>>2)*4+nt)*4+(col&3)
// conv down layers (fused skip): K=640, N=64, co=nt*16+col
// mlp L0-L3: 16-wide n-tiles, k=kc*32+quad*8+j, n=nt*16+col
//   (fragment layout is A/B-symmetric: same data serves as the A operand for C=W*X)
__global__ __launch_bounds__(256) void k_repack_all(const float* __restrict__ cvt, u16* __restrict__ dst){
  int idx = blockIdx.x*256 + threadIdx.x;   // covers REPACK_TOTAL exactly
  float v;
  if (idx < 442368){
    int seg = idx / 147456, base = idx % 147456;
    const int wo[3] = {O_UP1W, O_UP2W, O_UP3W};
    int t = base & 511, c = base >> 9;      // c in [0,288)
    int j = t & 7, lane = t >> 3;
    int col = lane & 15, quad = lane >> 4;
    int kc = c >> 4, rem = c & 15;
    int wv = rem >> 2, nt = rem & 3;
    int k = kc*32 + quad*8 + j;             // < 576
    int kid = k >> 6, ci = k & 63;
    int co = (wv*16 + (col>>2)*4 + nt)*4 + (col&3);
    v = cvt[wo[seg] + co*576 + ci*9 + kid];
  } else if (idx < CONV_FRAG_TOTAL){
    int x = idx - 442368;
    int seg = x / 40960, base = x % 40960;
    int t = base & 511, c = base >> 9;      // c in [0,80)
    int j = t & 7, lane = t >> 3;
    int col = lane & 15, quad = lane >> 4;
    int kc = c >> 2, nt = c & 3;
    int k = kc*32 + quad*8 + j;
    int co = nt*16 + col;
    if (k < 576){
      int kid = k >> 6, ci = k & 63;
      v = cvt[(seg ? O_DN5W : O_DN4W) + co*576 + ci*9 + kid];
    } else {
      int ci = k - 576;
      v = cvt[(seg ? O_SK2W : O_SK1W) + co*64 + ci];
    }
  } else {
    int midx = idx - FG_MLP;
    int l, base;
    if (midx < FO_L1)      { l = 0; base = midx; }
    else if (midx < FO_L2) { l = 1; base = midx - FO_L1; }
    else if (midx < FO_L3) { l = 2; base = midx - FO_L2; }
    else if (midx < FO_L4) { l = 3; base = midx - FO_L3; }
    else                   { l = 4; base = midx - FO_L4; }
    int t = base & 511, c = base >> 9;
    int L = t >> 3, j = t & 7;
    int ntiles = (l == 4) ? 1 : 16;
    int kc = c / ntiles, nt = c % ntiles;
    int k = kc*32 + (L>>4)*8 + j;
    int n = nt*16 + (L&15);
    const int srcw[5] = {O_MLPW0, O_MLPW1, O_MLPW2, O_MLPW3, O_MLPW4};
    int Kvalid = (l == 0) ? 260 : 256;
    int N = (l == 4) ? 3 : 256;
    v = 0.f;
    if (k < Kvalid && n < N) v = cvt[srcw[l] + k*N + n];
  }
  dst[idx] = f2bf(v);
}

// ---------------- enc conv: 3->64, 3x3 pad1, NCHW fp32 in, NHWC bf16 out ----------------
__global__ __launch_bounds__(256) void k_enc(const float* __restrict__ cvt, u16* __restrict__ feat){
  int gid = blockIdx.x*256 + threadIdx.x;
  int co = gid & 63, pix = gid >> 6;
  int x = pix % 48; int t = pix / 48; int y = t % 48; int b = t / 48;
  const float* w = cvt + O_ENCW + co*27;
  float acc = cvt[O_ENCB + co];
  const float* ip = cvt + O_INP + b*3*2304;
  #pragma unroll
  for (int ci = 0; ci < 3; ++ci)
    for (int dy = 0; dy < 3; ++dy){
      int iy = y + dy - 1;
      for (int dx = 0; dx < 3; ++dx){
        int ix = x + dx - 1;
        float v = (iy>=0 && iy<48 && ix>=0 && ix<48) ? ip[ci*2304 + iy*48 + ix] : 0.f;
        acc = fmaf(w[ci*9 + dy*3 + dx], v, acc);
      }
    }
  feat[pix*64 + co] = f2bf(acc);
}

// ---------------- MFMA upconv 64->256 3x3 pad1 + fused pixel-shuffle, bf16 NHWC ----------------
template<int H>
__global__ __launch_bounds__(256,2) void k_upconv_mfma(const u16* __restrict__ in,
    const u16* __restrict__ wf, const float* __restrict__ bias, u16* __restrict__ out){
  __shared__ __align__(16) u16 patch[100*72];   // 10x10 px, 64ch + pad8
  const int TW = H/8;
  int b = blockIdx.y;
  int y0 = (blockIdx.x / TW)*8, x0 = (blockIdx.x % TW)*8;
  int tid = threadIdx.x;
  if (tid < 200){
    int p = tid >> 1, half = tid & 1;
    int pr = p/10, pc = p - pr*10;
    int gy = y0+pr-1, gx = x0+pc-1;
    uint4* dst = (uint4*)((char*)(patch + p*72) + half*64);
    if (gy>=0 && gy<H && gx>=0 && gx<H){
      const uint4* src = (const uint4*)((const char*)(in + ((b*H+gy)*H+gx)*64) + half*64);
      dst[0]=src[0]; dst[1]=src[1]; dst[2]=src[2]; dst[3]=src[3];
    } else {
      uint4 z = {0,0,0,0};
      dst[0]=z; dst[1]=z; dst[2]=z; dst[3]=z;
    }
  }
  __syncthreads();
  int lane = tid & 63, wv = __builtin_amdgcn_readfirstlane(tid>>6);
  int col = lane & 15, quad = lane >> 4;
  int rs = col & 3;                       // subpixel from low col bits
  int c2b = wv*16 + (col>>2)*4;           // 4 consecutive output channels per lane
  f32x4 acc[4][4];
  #pragma unroll
  for (int nt=0;nt<4;++nt){
    float bv = bias[(c2b + nt)*4 + rs];
    #pragma unroll
    for (int mt=0;mt<4;++mt) acc[mt][nt] = (f32x4){bv,bv,bv,bv};
  }
  int pyc[4], pxc[4];
  #pragma unroll
  for (int mt=0;mt<4;++mt){ int p = mt*16+col; pyc[mt]=p>>3; pxc[mt]=p&7; }
  #pragma unroll
  for (int kc=0; kc<18; ++kc){
    int dydx = kc>>1, half = kc&1;
    int dy = dydx/3, dx = dydx%3;
    bf16x8 a[4], bb[4];
    #pragma unroll
    for (int mt=0;mt<4;++mt)
      a[mt] = *(const bf16x8*)(patch + ((pyc[mt]+dy)*10 + pxc[mt]+dx)*72 + half*32 + quad*8);
    #pragma unroll
    for (int nt=0;nt<4;++nt)
      bb[nt] = *(const bf16x8*)(wf + ((kc*16 + wv*4 + nt)*64 + lane)*8);
    #pragma unroll
    for (int mt=0;mt<4;++mt)
      #pragma unroll
      for (int nt=0;nt<4;++nt)
        acc[mt][nt] = __builtin_amdgcn_mfma_f32_16x16x32_bf16(a[mt], bb[nt], acc[mt][nt], 0,0,0);
  }
  // store: per (mt,r) the 4 nt-values are channels c2b..c2b+3 at subpixel rs -> one 8B store
  const int W2 = 2*H;
  #pragma unroll
  for (int mt=0;mt<4;++mt)
    #pragma unroll
    for (int r=0;r<4;++r){
      int p = mt*16 + quad*4 + r;
      int oy = 2*(y0 + (p>>3)) + (rs>>1), ox = 2*(x0 + (p&7)) + (rs&1);
      uint2 v2;
      v2.x = pack2(acc[mt][0][r], acc[mt][1][r]);
      v2.y = pack2(acc[mt][2][r], acc[mt][3][r]);
      *(uint2*)(out + ((b*W2 + oy)*W2 + ox)*64 + c2b) = v2;
    }
}

// ---------------- MFMA stride-2 downconv 64->64 + fused 1x1 skip, bf16 NHWC ----------------
template<int HO>
__global__ __launch_bounds__(256,2) void k_down_mfma(const u16* __restrict__ in3,
    const u16* __restrict__ in2, const u16* __restrict__ wf,
    const float* __restrict__ biasd, const float* __restrict__ biass, u16* __restrict__ out){
  __shared__ __align__(16) u16 patch3[289*72];  // 17x17 px
  __shared__ __align__(16) u16 patch2[64*72];   // 8x8 px (skip input)
  const int HI = 2*HO, TW = HO/8;
  int b = blockIdx.y;
  int y0 = (blockIdx.x / TW)*8, x0 = (blockIdx.x % TW)*8;
  int tid = threadIdx.x;
  for (int u = tid; u < 578; u += 256){
    int p = u >> 1, half = u & 1;
    int pr = p/17, pc = p - pr*17;
    int gy = 2*y0 - 1 + pr, gx = 2*x0 - 1 + pc;
    uint4* dst = (uint4*)((char*)(patch3 + p*72) + half*64);
    if (gy>=0 && gy<HI && gx>=0 && gx<HI){
      const uint4* src = (const uint4*)((const char*)(in3 + ((b*HI+gy)*HI+gx)*64) + half*64);
      dst[0]=src[0]; dst[1]=src[1]; dst[2]=src[2]; dst[3]=src[3];
    } else { uint4 z={0,0,0,0}; dst[0]=z; dst[1]=z; dst[2]=z; dst[3]=z; }
  }
  if (tid < 128){
    int p = tid >> 1, half = tid & 1;
    int gy = y0 + (p>>3), gx = x0 + (p&7);
    uint4* dst = (uint4*)((char*)(patch2 + p*72) + half*64);
    const uint4* src = (const uint4*)((const char*)(in2 + ((b*HO+gy)*HO+gx)*64) + half*64);
    dst[0]=src[0]; dst[1]=src[1]; dst[2]=src[2]; dst[3]=src[3];
  }
  __syncthreads();
  int lane = tid & 63, wv = __builtin_amdgcn_readfirstlane(tid>>6);
  int col = lane & 15, quad = lane >> 4;
  f32x4 acc[4];
  {
    float bv = biasd[wv*16+col] + biass[wv*16+col];
    #pragma unroll
    for (int mt=0;mt<4;++mt) acc[mt] = (f32x4){bv,bv,bv,bv};
  }
  int pyc[4], pxc[4];
  #pragma unroll
  for (int mt=0;mt<4;++mt){ int p = mt*16+col; pyc[mt]=p>>3; pxc[mt]=p&7; }
  #pragma unroll
  for (int kc=0; kc<20; ++kc){
    bf16x8 a[4];
    if (kc < 18){
      int dydx = kc>>1, half = kc&1;
      int dy = dydx/3, dx = dydx%3;
      #pragma unroll
      for (int mt=0;mt<4;++mt)
        a[mt] = *(const bf16x8*)(patch3 + ((2*pyc[mt]+dy)*17 + 2*pxc[mt]+dx)*72 + half*32 + quad*8);
    } else {
      #pragma unroll
      for (int mt=0;mt<4;++mt)
        a[mt] = *(const bf16x8*)(patch2 + (pyc[mt]*8+pxc[mt])*72 + (kc-18)*32 + quad*8);
    }
    bf16x8 bb = *(const bf16x8*)(wf + ((kc*4 + wv)*64 + lane)*8);
    #pragma unroll
    for (int mt=0;mt<4;++mt)
      acc[mt] = __builtin_amdgcn_mfma_f32_16x16x32_bf16(a[mt], bb, acc[mt], 0,0,0);
  }
  #pragma unroll
  for (int mt=0;mt<4;++mt)
    #pragma unroll
    for (int r=0;r<4;++r){
      int p = mt*16 + quad*4 + r;
      out[((b*HO + y0+(p>>3))*HO + x0+(p&7))*64 + wv*16+col] = f2bf(acc[mt][r]);
    }
}

// ---------------- query stage helpers (fp32 op sequence matched to numpy) ----------------
DI void shifted_coord(float cy, float cx, int e, float& cy_, float& cx_){
  float vx = (e & 2) ? 1.f : -1.f;
  float vy = (e & 1) ? 1.f : -1.f;
  float sy = (float)((double)vx*(1.0/48.0) + 1e-6);
  float sx = (float)((double)vy*(1.0/48.0) + 1e-6);
  const float clo = (float)(-1.0 + 1e-6), chi = (float)(1.0 - 1e-6);
  cy_ = fminf(fmaxf(__fadd_rn(cy, sy), clo), chi);
  cx_ = fminf(fmaxf(__fadd_rn(cx, sx), clo), chi);
}
DI int nidx(float c_, int hL){
  float f = __fadd_rn(__fmul_rn(__fadd_rn(c_, 1.f), (float)hL*0.5f), -0.5f);
  int i = (int)rintf(f);
  return max(0, min(hL-1, i));
}

// ---------------- MFMA MLP layer helpers (16x16x32, C = W*X with weights as A) ----------------
// Fragment symmetry: packed weight tiles serve as A (m=lane&15 -> out-channel).
// C: m = out-ch = quad*4+reg, n = query-row = col -> 4 consecutive channels/lane -> b64 LDS store.
template<int KC>
DI void layer_compute(const u16* __restrict__ Xb, const u16* __restrict__ wf,
                      const float* __restrict__ bias, int lane, int wv, f32x4 (&acc)[4][4]){
  int col = lane & 15, quad = lane >> 4;
  #pragma unroll
  for (int mt=0;mt<4;++mt){
    f32x4 b4 = *(const f32x4*)(bias + wv*64 + mt*16 + quad*4);
    #pragma unroll
    for (int nt=0;nt<4;++nt) acc[mt][nt] = b4;
  }
  for (int kc=0; kc<KC; ++kc){
    bf16x8 w[4], x[4];
    #pragma unroll
    for (int mt=0;mt<4;++mt)
      w[mt] = *(const bf16x8*)(wf + ((kc*16 + wv*4 + mt)*64 + lane)*8);
    #pragma unroll
    for (int nt=0;nt<4;++nt)
      x[nt] = *(const bf16x8*)(Xb + (nt*16+col)*AST + kc*32 + quad*8);
    #pragma unroll
    for (int mt=0;mt<4;++mt)
      #pragma unroll
      for (int nt=0;nt<4;++nt)
        acc[mt][nt] = __builtin_amdgcn_mfma_f32_16x16x32_bf16(w[mt], x[nt], acc[mt][nt], 0, 0, 0);
  }
}

DI void layer_store(u16* __restrict__ Xb, f32x4 (&acc)[4][4], int lane, int wv){
  int col = lane & 15, quad = lane >> 4;
  #pragma unroll
  for (int nt=0;nt<4;++nt)
    #pragma unroll
    for (int mt=0;mt<4;++mt){
      uint2 v2;
      v2.x = pack2(fmaxf(acc[mt][nt][0], 0.f), fmaxf(acc[mt][nt][1], 0.f));
      v2.y = pack2(fmaxf(acc[mt][nt][2], 0.f), fmaxf(acc[mt][nt][3], 0.f));
      *(uint2*)(Xb + (nt*16+col)*AST + wv*64 + mt*16 + quad*4) = v2;
    }
}

// ---------------- fused gather + MFMA MLP + ensemble + bilinear ----------------
__global__ __launch_bounds__(256) void k_query(const float* __restrict__ cvt,
    const u16* __restrict__ feat, const u16* __restrict__ feat3,
    const u16* __restrict__ feat4, const u16* __restrict__ feat5,
    const u16* __restrict__ wfrag, const void* __restrict__ cellraw, void* __restrict__ outv){
  __shared__ __align__(16) u16 Abuf[64*AST];      // 37888 B, [row][channel]
  __shared__ float predbuf[64*3];
  int tid = threadIdx.x;

  // ---- gather: 64 rows (16 queries x 4 ensembles), 4 parts/row = 4 pyramid levels ----
  {
    int r = tid >> 2, part = tid & 3;
    int gq = blockIdx.x*16 + (r>>2);
    int e = r & 3;
    int b = gq >> 14, q = gq & 16383;
    float cy = cvt[O_COORD + (b*16384+q)*2 + 0];
    float cx = cvt[O_COORD + (b*16384+q)*2 + 1];
    float cy_, cx_; shifted_coord(cy, cx, e, cy_, cx_);
    int hL = (part==0) ? 48 : (part==1) ? 96 : (part==2) ? 192 : 384;
    const u16* fp = (part==0) ? feat : (part==1) ? feat5 : (part==2) ? feat4 : feat3;
    int iy = nidx(cy_, hL), ix = nidx(cx_, hL);
    const uint4* src = (const uint4*)(fp + ((b*hL + iy)*hL + ix)*64);
    uint4* dst = (uint4*)((char*)Abuf + r*(AST*2) + part*128);
    #pragma unroll
    for (int i=0;i<8;++i) dst[i] = src[i];
  }
  // ---- rel features into K=256..259, zeros to 287 (layer-0 K padded to 288) ----
  if (tid < 64){
    int gq = blockIdx.x*16 + (tid>>2);
    int e = tid & 3;
    int b = gq >> 14, q = gq & 16383;
    float cy = cvt[O_COORD + (b*16384+q)*2 + 0];
    float cx = cvt[O_COORD + (b*16384+q)*2 + 1];
    float cy_, cx_; shifted_coord(cy, cx, e, cy_, cx_);
    int iy = nidx(cy_, 48), ix = nidx(cx_, 48);
    float qy = -1.f + (2.f*iy + 1.f)*(1.f/48.f);
    float qx = -1.f + (2.f*ix + 1.f)*(1.f/48.f);
    float r0 = (cy - qy)*48.f;
    float r1 = (cx - qx)*48.f;
    float r2 = cvt[O_CELL + (b*16384+q)*2 + 0]*48.f;
    float r3 = cvt[O_CELL + (b*16384+q)*2 + 1]*48.f;
    u32* dst = (u32*)((char*)Abuf + tid*(AST*2) + 512);
    dst[0] = pack2(r0, r1);
    dst[1] = pack2(r2, r3);
    #pragma unroll
    for (int z=0; z<14; ++z) dst[2+z] = 0u;
  }
  __syncthreads();

  int lane = tid & 63;
  int wv = __builtin_amdgcn_readfirstlane(tid >> 6);

  { f32x4 acc[4][4];
    layer_compute<9>(Abuf, wfrag + FO_L0, cvt + O_MLPB0, lane, wv, acc);
    __syncthreads(); layer_store(Abuf, acc, lane, wv); }
  __syncthreads();
  { f32x4 acc[4][4];
    layer_compute<8>(Abuf, wfrag + FO_L1, cvt + O_MLPB1, lane, wv, acc);
    __syncthreads(); layer_store(Abuf, acc, lane, wv); }
  __syncthreads();
  { f32x4 acc[4][4];
    layer_compute<8>(Abuf, wfrag + FO_L2, cvt + O_MLPB2, lane, wv, acc);
    __syncthreads(); layer_store(Abuf, acc, lane, wv); }
  __syncthreads();
  { f32x4 acc[4][4];
    layer_compute<8>(Abuf, wfrag + FO_L3, cvt + O_MLPB3, lane, wv, acc);
    __syncthreads(); layer_store(Abuf, acc, lane, wv); }
  __syncthreads();

  // ---- layer 4 (256->3), swapped: C[m=ch][n=row], wave wv handles row-tile wv ----
  {
    int col = lane & 15, quad = lane >> 4;
    f32x4 a4;
    #pragma unroll
    for (int r=0;r<4;++r){
      int m = quad*4 + r;
      a4[r] = (m < 3) ? cvt[O_MLPB4 + m] : 0.f;
    }
    for (int kc=0; kc<8; ++kc){
      bf16x8 w8 = *(const bf16x8*)(wfrag + FO_L4 + (kc*64 + lane)*8);
      bf16x8 xv = *(const bf16x8*)(Abuf + (wv*16 + col)*AST + kc*32 + quad*8);
      a4 = __builtin_amdgcn_mfma_f32_16x16x32_bf16(w8, xv, a4, 0, 0, 0);
    }
    if (quad == 0){
      #pragma unroll
      for (int r=0;r<3;++r)
        predbuf[(wv*16 + col)*3 + r] = a4[r];
    }
  }
  __syncthreads();

  // ---- ensemble combine + bilinear(inp) + store ----
  if (tid < 16){
    int gq = blockIdx.x*16 + tid;
    int b = gq >> 14, q = gq & 16383;
    float cy = cvt[O_COORD + (b*16384+q)*2 + 0];
    float cx = cvt[O_COORD + (b*16384+q)*2 + 1];
    float a[4];
    #pragma unroll
    for (int e=0;e<4;++e){
      float cy_, cx_; shifted_coord(cy, cx, e, cy_, cx_);
      int iy = nidx(cy_, 48), ix = nidx(cx_, 48);
      float qy = -1.f + (2.f*iy + 1.f)*(1.f/48.f);
      float qx = -1.f + (2.f*ix + 1.f)*(1.f/48.f);
      float ry = (cy - qy)*48.f, rx = (cx - qx)*48.f;
      a[e] = fabsf(ry*rx) + 1e-9f;
    }
    float tot = a[0]+a[1]+a[2]+a[3];
    float fy = fminf(fmaxf((cy+1.f)*24.f - 0.5f, 0.f), 47.f);
    float fx = fminf(fmaxf((cx+1.f)*24.f - 0.5f, 0.f), 47.f);
    float y0f = floorf(fy), x0f = floorf(fx);
    float wy = fy - y0f, wx = fx - x0f;
    int y0 = (int)y0f, x0 = (int)x0f;
    int y1 = min(y0+1, 47), x1 = min(x0+1, 47);
    int bf = is_bf16(cellraw);
    #pragma unroll
    for (int ch=0; ch<3; ++ch){
      const float* ip = cvt + O_INP + (b*3 + ch)*2304;
      float v00 = ip[y0*48+x0], v01 = ip[y0*48+x1], v10 = ip[y1*48+x0], v11 = ip[y1*48+x1];
      float v = v00*(1.f-wy)*(1.f-wx) + v01*(1.f-wy)*wx + v10*wy*(1.f-wx) + v11*wy*wx;
      #pragma unroll
      for (int e=0;e<4;++e)
        v += predbuf[(tid*4+e)*3 + ch] * (a[3-e]/tot);   // local-ensemble diagonal swap
      int oi = (b*16384+q)*3 + ch;
      if (bf) ((u16*)outv)[oi] = f2bf(v);
      else    ((float*)outv)[oi] = v;
    }
  }
}

extern "C" void kernel_launch(void* const* d_in, const int* in_sizes, int n_in,
                              void* d_out, int out_size, void* d_ws, size_t ws_size,
                              hipStream_t stream){
  float* ws = (float*)d_ws;
  float* cvt = ws + W_CVT;
  u16* frag = (u16*)(ws + W_FRAG);
  u16* feat  = (u16*)(ws + W_FEAT);
  u16* feat1 = (u16*)(ws + W_FEAT1);
  u16* feat2 = (u16*)(ws + W_FEAT2);
  u16* feat3 = (u16*)(ws + W_FEAT3);
  u16* feat4 = (u16*)(ws + W_FEAT4);
  u16* feat5 = (u16*)(ws + W_FEAT5);
  Ptrs ptrs;
  for (int i = 0; i < NIN && i < n_in; ++i) ptrs.p[i] = d_in[i];

  k_convert<<<(CVT_TOTAL+255)/256, 256, 0, stream>>>(ptrs, cvt);
  k_repack_all<<<REPACK_TOTAL/256, 256, 0, stream>>>(cvt, frag);
  k_enc<<<2304, 256, 0, stream>>>(cvt, feat);
  k_upconv_mfma<48> <<<dim3(36, 4), 256, 0, stream>>>(feat,  frag+FG_UP1, cvt+O_UP1B, feat1);
  k_upconv_mfma<96> <<<dim3(144,4), 256, 0, stream>>>(feat1, frag+FG_UP2, cvt+O_UP2B, feat2);
  k_upconv_mfma<192><<<dim3(576,4), 256, 0, stream>>>(feat2, frag+FG_UP3, cvt+O_UP3B, feat3);
  k_down_mfma<192><<<dim3(576,4), 256, 0, stream>>>(feat3, feat2, frag+FG_D4, cvt+O_DN4B, cvt+O_SK1B, feat4);
  k_down_mfma<96> <<<dim3(144,4), 256, 0, stream>>>(feat4, feat1, frag+FG_D5, cvt+O_DN5B, cvt+O_SK2B, feat5);
  k_query<<<4096, 256, 0, stream>>>(cvt, feat, feat3, feat4, feat5, frag + FG_MLP, d_in[2], d_out);
}

// Round 9
// 387.782 us; speedup vs baseline: 1.0459x; 1.0190x over previous
//
#include <hip/hip_runtime.h>
#include <stdint.h>

typedef unsigned int u32;
typedef unsigned short u16;

#define DI __device__ __forceinline__

DI float bf2f(u16 h){ return __uint_as_float(((u32)h)<<16); }
// round-half-up bf16: 2 VALU ops (vs 4 for RNE); differs from RNE only on exact ties
DI u16 f2bf(float f){ return (u16)((__float_as_uint(f) + 0x8000u) >> 16); }
DI u32 pack2(float a, float b){
  u32 au = __float_as_uint(a) + 0x8000u;
  u32 bu = __float_as_uint(b) + 0x8000u;
  return (au >> 16) | (bu & 0xFFFF0000u);
}
DI int is_bf16(const void* p){ u32 u = *(const u32*)p; return ((u>>16) == (u & 0xFFFFu)) ? 1 : 0; }

typedef __attribute__((ext_vector_type(8))) short bf16x8;
typedef __attribute__((ext_vector_type(4))) float f32x4;

// ---------------- input table (element counts / offsets in fp32 staging buf) ----------------
#define NIN 29
__device__ const int g_in_off[NIN] = {
  0,27648,158720,289792,291520,291584,439040,439296,586752,587008,734464,
  734720,738816,738880,742976,743040,779904,779968,816832,816896,883456,
  883712,949248,949504,1015040,1015296,1080832,1081088,1081856};
#define CVT_TOTAL 1081859

// cvt-buffer float offsets
#define O_INP      0
#define O_COORD    27648
#define O_CELL     158720
#define O_ENCW     289792
#define O_ENCB     291520
#define O_UP1W     291584
#define O_UP1B     439040
#define O_UP2W     439296
#define O_UP2B     586752
#define O_UP3W     587008
#define O_UP3B     734464
#define O_SK1W     734720
#define O_SK1B     738816
#define O_SK2W     738880
#define O_SK2B     742976
#define O_DN4W     743040
#define O_DN4B     779904
#define O_DN5W     779968
#define O_DN5B     816832
#define O_MLPW0    816896
#define O_MLPB0    883456
#define O_MLPW1    883712
#define O_MLPB1    949248
#define O_MLPW2    949504
#define O_MLPB2    1015040
#define O_MLPW3    1015296
#define O_MLPB3    1080832
#define O_MLPW4    1081088
#define O_MLPB4    1081856

// ---------------- workspace layout (float offsets) ----------------
#define W_CVT    16
#define W_FRAG   1082000     // u16 fragment region (conv + mlp), 798720 u16
// fragment sub-offsets (u16 elements within W_FRAG)
#define FG_UP1 0
#define FG_UP2 147456
#define FG_UP3 294912
#define FG_D4  442368
#define FG_D5  483328
#define CONV_FRAG_TOTAL 524288
#define FG_MLP 524288
// MLP fragment layer offsets (u16, relative to FG_MLP)
#define FO_L0 0
#define FO_L1 73728
#define FO_L2 139264
#define FO_L3 204800
#define FO_L4 270336
#define FRAG_TOTAL 274432
#define REPACK_TOTAL (CONV_FRAG_TOTAL + FRAG_TOTAL)   // 798720 = 3120*256
// feature maps: bf16 NHWC (float offsets; cast to u16*)
#define W_FEAT   1481360    // 48x48x64 x4  -> ends 1776272
#define W_FEAT1  1776272    // 96          -> ends 2955920
#define W_FEAT2  2955920    // 192         -> ends 7674512
#define W_FEAT3  7674512    // 384         -> ends 26548880
#define W_FEAT4  26548880   // 192         -> ends 31267472
#define W_FEAT5  31267472   // 96          -> ends 32447120
// end: 32447120 floats = 129.8 MB

#define AST 296   // Abuf row stride in bf16 (592 B: 16B-aligned, bank step 20 -> <=2-way)

struct Ptrs { const void* p[NIN]; };

__global__ __launch_bounds__(256) void k_convert(Ptrs ptrs, float* __restrict__ dst){
  int idx = blockIdx.x*256 + threadIdx.x;
  if (idx >= CVT_TOTAL) return;
  int bf = is_bf16(ptrs.p[2]);   // cell is constant 2/384: packed-bf16 halves match
  int i = 0;
  #pragma unroll
  for (int s = 1; s < NIN; ++s) if (idx >= g_in_off[s]) i = s;
  int local = idx - g_in_off[i];
  float v;
  if (bf) v = bf2f(((const u16*)ptrs.p[i])[local]);
  else    v = ((const float*)ptrs.p[i])[local];
  dst[idx] = v;
}

// ---------------- merged weight repack -> MFMA fragment order (bf16) ----------------
// conv up layers: K=576 (k=(dy*3+dx)*64+ci), N=256, perm co=(wv*16+(col>>2)*4+nt)*4+(col&3)
// conv down layers (fused skip): K=640, N=64, co=nt*16+col
// mlp L0-L3: 16-wide n-tiles, k=kc*32+quad*8+j, n=nt*16+col
//   (fragment layout is A/B-symmetric: same data serves as the A operand for C=W*X)
__global__ __launch_bounds__(256) void k_repack_all(const float* __restrict__ cvt, u16* __restrict__ dst){
  int idx = blockIdx.x*256 + threadIdx.x;   // covers REPACK_TOTAL exactly
  float v;
  if (idx < 442368){
    int seg = idx / 147456, base = idx % 147456;
    const int wo[3] = {O_UP1W, O_UP2W, O_UP3W};
    int t = base & 511, c = base >> 9;      // c in [0,288)
    int j = t & 7, lane = t >> 3;
    int col = lane & 15, quad = lane >> 4;
    int kc = c >> 4, rem = c & 15;
    int wv = rem >> 2, nt = rem & 3;
    int k = kc*32 + quad*8 + j;             // < 576
    int kid = k >> 6, ci = k & 63;
    int co = (wv*16 + (col>>2)*4 + nt)*4 + (col&3);
    v = cvt[wo[seg] + co*576 + ci*9 + kid];
  } else if (idx < CONV_FRAG_TOTAL){
    int x = idx - 442368;
    int seg = x / 40960, base = x % 40960;
    int t = base & 511, c = base >> 9;      // c in [0,80)
    int j = t & 7, lane = t >> 3;
    int col = lane & 15, quad = lane >> 4;
    int kc = c >> 2, nt = c & 3;
    int k = kc*32 + quad*8 + j;
    int co = nt*16 + col;
    if (k < 576){
      int kid = k >> 6, ci = k & 63;
      v = cvt[(seg ? O_DN5W : O_DN4W) + co*576 + ci*9 + kid];
    } else {
      int ci = k - 576;
      v = cvt[(seg ? O_SK2W : O_SK1W) + co*64 + ci];
    }
  } else {
    int midx = idx - FG_MLP;
    int l, base;
    if (midx < FO_L1)      { l = 0; base = midx; }
    else if (midx < FO_L2) { l = 1; base = midx - FO_L1; }
    else if (midx < FO_L3) { l = 2; base = midx - FO_L2; }
    else if (midx < FO_L4) { l = 3; base = midx - FO_L3; }
    else                   { l = 4; base = midx - FO_L4; }
    int t = base & 511, c = base >> 9;
    int L = t >> 3, j = t & 7;
    int ntiles = (l == 4) ? 1 : 16;
    int kc = c / ntiles, nt = c % ntiles;
    int k = kc*32 + (L>>4)*8 + j;
    int n = nt*16 + (L&15);
    const int srcw[5] = {O_MLPW0, O_MLPW1, O_MLPW2, O_MLPW3, O_MLPW4};
    int Kvalid = (l == 0) ? 260 : 256;
    int N = (l == 4) ? 3 : 256;
    v = 0.f;
    if (k < Kvalid && n < N) v = cvt[srcw[l] + k*N + n];
  }
  dst[idx] = f2bf(v);
}

// ---------------- enc conv: 3->64, 3x3 pad1, NCHW fp32 in, NHWC bf16 out ----------------
__global__ __launch_bounds__(256) void k_enc(const float* __restrict__ cvt, u16* __restrict__ feat){
  int gid = blockIdx.x*256 + threadIdx.x;
  int co = gid & 63, pix = gid >> 6;
  int x = pix % 48; int t = pix / 48; int y = t % 48; int b = t / 48;
  const float* w = cvt + O_ENCW + co*27;
  float acc = cvt[O_ENCB + co];
  const float* ip = cvt + O_INP + b*3*2304;
  #pragma unroll
  for (int ci = 0; ci < 3; ++ci)
    for (int dy = 0; dy < 3; ++dy){
      int iy = y + dy - 1;
      for (int dx = 0; dx < 3; ++dx){
        int ix = x + dx - 1;
        float v = (iy>=0 && iy<48 && ix>=0 && ix<48) ? ip[ci*2304 + iy*48 + ix] : 0.f;
        acc = fmaf(w[ci*9 + dy*3 + dx], v, acc);
      }
    }
  feat[pix*64 + co] = f2bf(acc);
}

// ---------------- MFMA upconv 64->256 3x3 pad1 + fused pixel-shuffle, bf16 NHWC ----------------
template<int H>
__global__ __launch_bounds__(256,2) void k_upconv_mfma(const u16* __restrict__ in,
    const u16* __restrict__ wf, const float* __restrict__ bias, u16* __restrict__ out){
  __shared__ __align__(16) u16 patch[100*72];   // 10x10 px, 64ch + pad8
  const int TW = H/8;
  int b = blockIdx.y;
  int y0 = (blockIdx.x / TW)*8, x0 = (blockIdx.x % TW)*8;
  int tid = threadIdx.x;
  if (tid < 200){
    int p = tid >> 1, half = tid & 1;
    int pr = p/10, pc = p - pr*10;
    int gy = y0+pr-1, gx = x0+pc-1;
    uint4* dst = (uint4*)((char*)(patch + p*72) + half*64);
    if (gy>=0 && gy<H && gx>=0 && gx<H){
      const uint4* src = (const uint4*)((const char*)(in + ((b*H+gy)*H+gx)*64) + half*64);
      dst[0]=src[0]; dst[1]=src[1]; dst[2]=src[2]; dst[3]=src[3];
    } else {
      uint4 z = {0,0,0,0};
      dst[0]=z; dst[1]=z; dst[2]=z; dst[3]=z;
    }
  }
  __syncthreads();
  int lane = tid & 63, wv = __builtin_amdgcn_readfirstlane(tid>>6);
  int col = lane & 15, quad = lane >> 4;
  int rs = col & 3;                       // subpixel from low col bits
  int c2b = wv*16 + (col>>2)*4;           // 4 consecutive output channels per lane
  f32x4 acc[4][4];
  #pragma unroll
  for (int nt=0;nt<4;++nt){
    float bv = bias[(c2b + nt)*4 + rs];
    #pragma unroll
    for (int mt=0;mt<4;++mt) acc[mt][nt] = (f32x4){bv,bv,bv,bv};
  }
  int pyc[4], pxc[4];
  #pragma unroll
  for (int mt=0;mt<4;++mt){ int p = mt*16+col; pyc[mt]=p>>3; pxc[mt]=p&7; }
  #pragma unroll
  for (int kc=0; kc<18; ++kc){
    int dydx = kc>>1, half = kc&1;
    int dy = dydx/3, dx = dydx%3;
    bf16x8 a[4], bb[4];
    #pragma unroll
    for (int mt=0;mt<4;++mt)
      a[mt] = *(const bf16x8*)(patch + ((pyc[mt]+dy)*10 + pxc[mt]+dx)*72 + half*32 + quad*8);
    #pragma unroll
    for (int nt=0;nt<4;++nt)
      bb[nt] = *(const bf16x8*)(wf + ((kc*16 + wv*4 + nt)*64 + lane)*8);
    #pragma unroll
    for (int mt=0;mt<4;++mt)
      #pragma unroll
      for (int nt=0;nt<4;++nt)
        acc[mt][nt] = __builtin_amdgcn_mfma_f32_16x16x32_bf16(a[mt], bb[nt], acc[mt][nt], 0,0,0);
  }
  // store: per (mt,r) the 4 nt-values are channels c2b..c2b+3 at subpixel rs -> one 8B store
  const int W2 = 2*H;
  #pragma unroll
  for (int mt=0;mt<4;++mt)
    #pragma unroll
    for (int r=0;r<4;++r){
      int p = mt*16 + quad*4 + r;
      int oy = 2*(y0 + (p>>3)) + (rs>>1), ox = 2*(x0 + (p&7)) + (rs&1);
      uint2 v2;
      v2.x = pack2(acc[mt][0][r], acc[mt][1][r]);
      v2.y = pack2(acc[mt][2][r], acc[mt][3][r]);
      *(uint2*)(out + ((b*W2 + oy)*W2 + ox)*64 + c2b) = v2;
    }
}

// ---------------- MFMA stride-2 downconv 64->64 + fused 1x1 skip, bf16 NHWC ----------------
template<int HO>
__global__ __launch_bounds__(256,2) void k_down_mfma(const u16* __restrict__ in3,
    const u16* __restrict__ in2, const u16* __restrict__ wf,
    const float* __restrict__ biasd, const float* __restrict__ biass, u16* __restrict__ out){
  __shared__ __align__(16) u16 patch3[289*72];  // 17x17 px
  __shared__ __align__(16) u16 patch2[64*72];   // 8x8 px (skip input)
  const int HI = 2*HO, TW = HO/8;
  int b = blockIdx.y;
  int y0 = (blockIdx.x / TW)*8, x0 = (blockIdx.x % TW)*8;
  int tid = threadIdx.x;
  for (int u = tid; u < 578; u += 256){
    int p = u >> 1, half = u & 1;
    int pr = p/17, pc = p - pr*17;
    int gy = 2*y0 - 1 + pr, gx = 2*x0 - 1 + pc;
    uint4* dst = (uint4*)((char*)(patch3 + p*72) + half*64);
    if (gy>=0 && gy<HI && gx>=0 && gx<HI){
      const uint4* src = (const uint4*)((const char*)(in3 + ((b*HI+gy)*HI+gx)*64) + half*64);
      dst[0]=src[0]; dst[1]=src[1]; dst[2]=src[2]; dst[3]=src[3];
    } else { uint4 z={0,0,0,0}; dst[0]=z; dst[1]=z; dst[2]=z; dst[3]=z; }
  }
  if (tid < 128){
    int p = tid >> 1, half = tid & 1;
    int gy = y0 + (p>>3), gx = x0 + (p&7);
    uint4* dst = (uint4*)((char*)(patch2 + p*72) + half*64);
    const uint4* src = (const uint4*)((const char*)(in2 + ((b*HO+gy)*HO+gx)*64) + half*64);
    dst[0]=src[0]; dst[1]=src[1]; dst[2]=src[2]; dst[3]=src[3];
  }
  __syncthreads();
  int lane = tid & 63, wv = __builtin_amdgcn_readfirstlane(tid>>6);
  int col = lane & 15, quad = lane >> 4;
  f32x4 acc[4];
  {
    float bv = biasd[wv*16+col] + biass[wv*16+col];
    #pragma unroll
    for (int mt=0;mt<4;++mt) acc[mt] = (f32x4){bv,bv,bv,bv};
  }
  int pyc[4], pxc[4];
  #pragma unroll
  for (int mt=0;mt<4;++mt){ int p = mt*16+col; pyc[mt]=p>>3; pxc[mt]=p&7; }
  #pragma unroll
  for (int kc=0; kc<20; ++kc){
    bf16x8 a[4];
    if (kc < 18){
      int dydx = kc>>1, half = kc&1;
      int dy = dydx/3, dx = dydx%3;
      #pragma unroll
      for (int mt=0;mt<4;++mt)
        a[mt] = *(const bf16x8*)(patch3 + ((2*pyc[mt]+dy)*17 + 2*pxc[mt]+dx)*72 + half*32 + quad*8);
    } else {
      #pragma unroll
      for (int mt=0;mt<4;++mt)
        a[mt] = *(const bf16x8*)(patch2 + (pyc[mt]*8+pxc[mt])*72 + (kc-18)*32 + quad*8);
    }
    bf16x8 bb = *(const bf16x8*)(wf + ((kc*4 + wv)*64 + lane)*8);
    #pragma unroll
    for (int mt=0;mt<4;++mt)
      acc[mt] = __builtin_amdgcn_mfma_f32_16x16x32_bf16(a[mt], bb, acc[mt], 0,0,0);
  }
  #pragma unroll
  for (int mt=0;mt<4;++mt)
    #pragma unroll
    for (int r=0;r<4;++r){
      int p = mt*16 + quad*4 + r;
      out[((b*HO + y0+(p>>3))*HO + x0+(p&7))*64 + wv*16+col] = f2bf(acc[mt][r]);
    }
}

// ---------------- query stage helpers (fp32 op sequence matched to numpy) ----------------
DI void shifted_coord(float cy, float cx, int e, float& cy_, float& cx_){
  float vx = (e & 2) ? 1.f : -1.f;
  float vy = (e & 1) ? 1.f : -1.f;
  float sy = (float)((double)vx*(1.0/48.0) + 1e-6);
  float sx = (float)((double)vy*(1.0/48.0) + 1e-6);
  const float clo = (float)(-1.0 + 1e-6), chi = (float)(1.0 - 1e-6);
  cy_ = fminf(fmaxf(__fadd_rn(cy, sy), clo), chi);
  cx_ = fminf(fmaxf(__fadd_rn(cx, sx), clo), chi);
}
DI int nidx(float c_, int hL){
  float f = __fadd_rn(__fmul_rn(__fadd_rn(c_, 1.f), (float)hL*0.5f), -0.5f);
  int i = (int)rintf(f);
  return max(0, min(hL-1, i));
}

// ---------------- MFMA MLP layer helpers (16x16x32, C = W*X with weights as A) ----------------
// All hot loads/stores: single base pointer + compile-time immediate offsets (full unroll).
// X reads:  xp + kc*64B + nt*9472B   (ds_read_b128 16-bit imm, max 28928)
// W reads:  wp + kc*16KB + mt*1024B  (global 13-bit imm covers mt; one add per kc)
// C stores: sp + nt*9472B + mt*32B   (ds_write_b64 imm)
template<int KC>
DI void layer_compute(const u16* __restrict__ Xb, const u16* __restrict__ wf,
                      const float* __restrict__ bias, int lane, int wv, f32x4 (&acc)[4][4]){
  int col = lane & 15, quad = lane >> 4;
  #pragma unroll
  for (int mt=0;mt<4;++mt){
    f32x4 b4 = *(const f32x4*)(bias + wv*64 + mt*16 + quad*4);
    #pragma unroll
    for (int nt=0;nt<4;++nt) acc[mt][nt] = b4;
  }
  const u16* xp = Xb + col*AST + quad*8;
  const u16* wp = wf + (wv*4*64 + lane)*8;
  #pragma unroll
  for (int kc=0; kc<KC; ++kc){
    bf16x8 w[4], x[4];
    #pragma unroll
    for (int mt=0;mt<4;++mt)
      w[mt] = *(const bf16x8*)(wp + kc*8192 + mt*512);
    #pragma unroll
    for (int nt=0;nt<4;++nt)
      x[nt] = *(const bf16x8*)(xp + kc*32 + nt*16*AST);
    #pragma unroll
    for (int mt=0;mt<4;++mt)
      #pragma unroll
      for (int nt=0;nt<4;++nt)
        acc[mt][nt] = __builtin_amdgcn_mfma_f32_16x16x32_bf16(w[mt], x[nt], acc[mt][nt], 0, 0, 0);
  }
}

DI void layer_store(u16* __restrict__ Xb, f32x4 (&acc)[4][4], int lane, int wv){
  int col = lane & 15, quad = lane >> 4;
  u16* sp = Xb + col*AST + wv*64 + quad*4;
  #pragma unroll
  for (int nt=0;nt<4;++nt)
    #pragma unroll
    for (int mt=0;mt<4;++mt){
      uint2 v2;
      v2.x = pack2(fmaxf(acc[mt][nt][0], 0.f), fmaxf(acc[mt][nt][1], 0.f));
      v2.y = pack2(fmaxf(acc[mt][nt][2], 0.f), fmaxf(acc[mt][nt][3], 0.f));
      *(uint2*)(sp + nt*16*AST + mt*16) = v2;
    }
}

// ---------------- fused gather + MFMA MLP + ensemble + bilinear ----------------
__global__ __launch_bounds__(256) void k_query(const float* __restrict__ cvt,
    const u16* __restrict__ feat, const u16* __restrict__ feat3,
    const u16* __restrict__ feat4, const u16* __restrict__ feat5,
    const u16* __restrict__ wfrag, const void* __restrict__ cellraw, void* __restrict__ outv){
  __shared__ __align__(16) u16 Abuf[64*AST];      // 37888 B, [row][channel]
  __shared__ float predbuf[64*3];
  int tid = threadIdx.x;

  // ---- gather: 64 rows (16 queries x 4 ensembles), 4 parts/row = 4 pyramid levels ----
  {
    int r = tid >> 2, part = tid & 3;
    int gq = blockIdx.x*16 + (r>>2);
    int e = r & 3;
    int b = gq >> 14, q = gq & 16383;
    float cy = cvt[O_COORD + (b*16384+q)*2 + 0];
    float cx = cvt[O_COORD + (b*16384+q)*2 + 1];
    float cy_, cx_; shifted_coord(cy, cx, e, cy_, cx_);
    int hL = (part==0) ? 48 : (part==1) ? 96 : (part==2) ? 192 : 384;
    const u16* fp = (part==0) ? feat : (part==1) ? feat5 : (part==2) ? feat4 : feat3;
    int iy = nidx(cy_, hL), ix = nidx(cx_, hL);
    const uint4* src = (const uint4*)(fp + ((b*hL + iy)*hL + ix)*64);
    uint4* dst = (uint4*)((char*)Abuf + r*(AST*2) + part*128);
    #pragma unroll
    for (int i=0;i<8;++i) dst[i] = src[i];
  }
  // ---- rel features into K=256..259, zeros to 287 (layer-0 K padded to 288) ----
  if (tid < 64){
    int gq = blockIdx.x*16 + (tid>>2);
    int e = tid & 3;
    int b = gq >> 14, q = gq & 16383;
    float cy = cvt[O_COORD + (b*16384+q)*2 + 0];
    float cx = cvt[O_COORD + (b*16384+q)*2 + 1];
    float cy_, cx_; shifted_coord(cy, cx, e, cy_, cx_);
    int iy = nidx(cy_, 48), ix = nidx(cx_, 48);
    float qy = -1.f + (2.f*iy + 1.f)*(1.f/48.f);
    float qx = -1.f + (2.f*ix + 1.f)*(1.f/48.f);
    float r0 = (cy - qy)*48.f;
    float r1 = (cx - qx)*48.f;
    float r2 = cvt[O_CELL + (b*16384+q)*2 + 0]*48.f;
    float r3 = cvt[O_CELL + (b*16384+q)*2 + 1]*48.f;
    u32* dst = (u32*)((char*)Abuf + tid*(AST*2) + 512);
    dst[0] = pack2(r0, r1);
    dst[1] = pack2(r2, r3);
    #pragma unroll
    for (int z=0; z<14; ++z) dst[2+z] = 0u;
  }
  __syncthreads();

  int lane = tid & 63;
  int wv = __builtin_amdgcn_readfirstlane(tid >> 6);

  { f32x4 acc[4][4];
    layer_compute<9>(Abuf, wfrag + FO_L0, cvt + O_MLPB0, lane, wv, acc);
    __syncthreads(); layer_store(Abuf, acc, lane, wv); }
  __syncthreads();
  { f32x4 acc[4][4];
    layer_compute<8>(Abuf, wfrag + FO_L1, cvt + O_MLPB1, lane, wv, acc);
    __syncthreads(); layer_store(Abuf, acc, lane, wv); }
  __syncthreads();
  { f32x4 acc[4][4];
    layer_compute<8>(Abuf, wfrag + FO_L2, cvt + O_MLPB2, lane, wv, acc);
    __syncthreads(); layer_store(Abuf, acc, lane, wv); }
  __syncthreads();
  { f32x4 acc[4][4];
    layer_compute<8>(Abuf, wfrag + FO_L3, cvt + O_MLPB3, lane, wv, acc);
    __syncthreads(); layer_store(Abuf, acc, lane, wv); }
  __syncthreads();

  // ---- layer 4 (256->3), swapped: C[m=ch][n=row], wave wv handles row-tile wv ----
  {
    int col = lane & 15, quad = lane >> 4;
    f32x4 a4;
    #pragma unroll
    for (int r=0;r<4;++r){
      int m = quad*4 + r;
      a4[r] = (m < 3) ? cvt[O_MLPB4 + m] : 0.f;
    }
    const u16* xp4 = Abuf + (wv*16 + col)*AST + quad*8;
    const u16* wp4 = wfrag + FO_L4 + lane*8;
    #pragma unroll
    for (int kc=0; kc<8; ++kc){
      bf16x8 w8 = *(const bf16x8*)(wp4 + kc*512);
      bf16x8 xv = *(const bf16x8*)(xp4 + kc*32);
      a4 = __builtin_amdgcn_mfma_f32_16x16x32_bf16(w8, xv, a4, 0, 0, 0);
    }
    if (quad == 0){
      #pragma unroll
      for (int r=0;r<3;++r)
        predbuf[(wv*16 + col)*3 + r] = a4[r];
    }
  }
  __syncthreads();

  // ---- ensemble combine + bilinear(inp) + store ----
  if (tid < 16){
    int gq = blockIdx.x*16 + tid;
    int b = gq >> 14, q = gq & 16383;
    float cy = cvt[O_COORD + (b*16384+q)*2 + 0];
    float cx = cvt[O_COORD + (b*16384+q)*2 + 1];
    float a[4];
    #pragma unroll
    for (int e=0;e<4;++e){
      float cy_, cx_; shifted_coord(cy, cx, e, cy_, cx_);
      int iy = nidx(cy_, 48), ix = nidx(cx_, 48);
      float qy = -1.f + (2.f*iy + 1.f)*(1.f/48.f);
      float qx = -1.f + (2.f*ix + 1.f)*(1.f/48.f);
      float ry = (cy - qy)*48.f, rx = (cx - qx)*48.f;
      a[e] = fabsf(ry*rx) + 1e-9f;
    }
    float tot = a[0]+a[1]+a[2]+a[3];
    float fy = fminf(fmaxf((cy+1.f)*24.f - 0.5f, 0.f), 47.f);
    float fx = fminf(fmaxf((cx+1.f)*24.f - 0.5f, 0.f), 47.f);
    float y0f = floorf(fy), x0f = floorf(fx);
    float wy = fy - y0f, wx = fx - x0f;
    int y0 = (int)y0f, x0 = (int)x0f;
    int y1 = min(y0+1, 47), x1 = min(x0+1, 47);
    int bf = is_bf16(cellraw);
    #pragma unroll
    for (int ch=0; ch<3; ++ch){
      const float* ip = cvt + O_INP + (b*3 + ch)*2304;
      float v00 = ip[y0*48+x0], v01 = ip[y0*48+x1], v10 = ip[y1*48+x0], v11 = ip[y1*48+x1];
      float v = v00*(1.f-wy)*(1.f-wx) + v01*(1.f-wy)*wx + v10*wy*(1.f-wx) + v11*wy*wx;
      #pragma unroll
      for (int e=0;e<4;++e)
        v += predbuf[(tid*4+e)*3 + ch] * (a[3-e]/tot);   // local-ensemble diagonal swap
      int oi = (b*16384+q)*3 + ch;
      if (bf) ((u16*)outv)[oi] = f2bf(v);
      else    ((float*)outv)[oi] = v;
    }
  }
}

extern "C" void kernel_launch(void* const* d_in, const int* in_sizes, int n_in,
                              void* d_out, int out_size, void* d_ws, size_t ws_size,
                              hipStream_t stream){
  float* ws = (float*)d_ws;
  float* cvt = ws + W_CVT;
  u16* frag = (u16*)(ws + W_FRAG);
  u16* feat  = (u16*)(ws + W_FEAT);
  u16* feat1 = (u16*)(ws + W_FEAT1);
  u16* feat2 = (u16*)(ws + W_FEAT2);
  u16* feat3 = (u16*)(ws + W_FEAT3);
  u16* feat4 = (u16*)(ws + W_FEAT4);
  u16* feat5 = (u16*)(ws + W_FEAT5);
  Ptrs ptrs;
  for (int i = 0; i < NIN && i < n_in; ++i) ptrs.p[i] = d_in[i];

  k_convert<<<(CVT_TOTAL+255)/256, 256, 0, stream>>>(ptrs, cvt);
  k_repack_all<<<REPACK_TOTAL/256, 256, 0, stream>>>(cvt, frag);
  k_enc<<<2304, 256, 0, stream>>>(cvt, feat);
  k_upconv_mfma<48> <<<dim3(36, 4), 256, 0, stream>>>(feat,  frag+FG_UP1, cvt+O_UP1B, feat1);
  k_upconv_mfma<96> <<<dim3(144,4), 256, 0, stream>>>(feat1, frag+FG_UP2, cvt+O_UP2B, feat2);
  k_upconv_mfma<192><<<dim3(576,4), 256, 0, stream>>>(feat2, frag+FG_UP3, cvt+O_UP3B, feat3);
  k_down_mfma<192><<<dim3(576,4), 256, 0, stream>>>(feat3, feat2, frag+FG_D4, cvt+O_DN4B, cvt+O_SK1B, feat4);
  k_down_mfma<96> <<<dim3(144,4), 256, 0, stream>>>(feat4, feat1, frag+FG_D5, cvt+O_DN5B, cvt+O_SK2B, feat5);
  k_query<<<4096, 256, 0, stream>>>(cvt, feat, feat3, feat4, feat5, frag + FG_MLP, d_in[2], d_out);
}